// Round 10
// baseline (880.643 us; speedup 1.0000x reference)
//
#include <hip/hip_runtime.h>
#include <math.h>

#define NBOND 7
#define NLAY 8
#define NTYPE 6
#define NNODES 16384   // B*N = 128*128
#define PX 136         // LDS pitch in halves (272 B, 16B-aligned; 68 dw % 32 = 4 -> conflict-clean)
#define NDESC 264      // 8 XCDs x 33 desc slots (>= 262 max active 64-node slices)

typedef _Float16 half8 __attribute__((ext_vector_type(8)));
typedef _Float16 half4 __attribute__((ext_vector_type(4)));
typedef float floatx16 __attribute__((ext_vector_type(16)));

__device__ __forceinline__ float sig_(float x) { return 1.0f / (1.0f + __expf(-x)); }
// D-layout for 32x32 MFMA: col = lane&31, row = (reg&3) + 8*(reg>>2) + 4*(lane>>5)
__device__ __forceinline__ int drow_(int reg, int hi) { return (reg & 3) + 8 * (reg >> 2) + 4 * hi; }

__device__ __forceinline__ _Float16 hi_(float v) { return (_Float16)v; }
__device__ __forceinline__ _Float16 lo_(float v) { return (_Float16)(v - (float)(_Float16)v); }

// ---------------------------------------------------------------- setup
__global__ void setup_kernel(const float* __restrict__ h, float* __restrict__ hT,
                             int* __restrict__ counts, int* __restrict__ bucket)
{
    int gid = blockIdx.x * 256 + threadIdx.x;
    int node = gid >> 7, d = gid & 127;
    hT[gid] = (d < 75) ? h[node * 75 + d] : 0.0f;
    if (gid < NNODES) {
        float a = h[gid * 75];
        int tt = 5;
        if      (a == 6.0f) tt = 0;
        else if (a == 7.0f) tt = 1;
        else if (a == 8.0f) tt = 2;
        else if (a == 9.0f) tt = 3;
        else if (a == 0.0f) tt = 4;
        int slot = atomicAdd(&counts[tt], 1);
        bucket[tt * NNODES + slot] = gid;
    }
}

// Dense GRU block descriptors over 64-node slices: desc[i] = tt | (slice<<3).
__global__ void build_desc_kernel(const int* __restrict__ counts, int* __restrict__ desc)
{
    if (threadIdx.x != 0 || blockIdx.x != 0) return;
    int i = 0;
    for (int tt = 0; tt < NTYPE; ++tt) {
        int nb = (counts[tt] + 63) >> 6;
        for (int s = 0; s < nb; ++s) desc[i++] = tt | (s << 3);
    }
    while (i < NDESC) desc[i++] = -1;
}

// ---------------------------------------------------------------- weight packing (fp32 -> split fp16 hi/lo planes)
// msgW: [(kb*8+l)][c 0..15][plane hi/lo][e 0..127][j 0..7]  (j along input dim d)
__global__ void pack_msg_kernel(const float* __restrict__ msgW, _Float16* __restrict__ Wp)
{
    int idx = blockIdx.x * 256 + threadIdx.x;
    if (idx >= NBOND * NLAY * 16 * 128) return;
    int e  = idx & 127;
    int c  = (idx >> 7) & 15;
    int kl = idx >> 11;
    const float* src = msgW + ((size_t)kl * 128 + e) * 128 + c * 8;
    float4 u = *(const float4*)src;
    float4 v = *(const float4*)(src + 4);
    float av[8] = {u.x, u.y, u.z, u.w, v.x, v.y, v.z, v.w};
    half8 hh, ll;
    #pragma unroll
    for (int j = 0; j < 8; ++j) { hh[j] = hi_(av[j]); ll[j] = lo_(av[j]); }
    _Float16* dst = Wp + ((size_t)kl * 16 + c) * 2048;
    *(half8*)(dst + e * 8)        = hh;
    *(half8*)(dst + 1024 + e * 8) = ll;
}

// GRU: [(vt*2+mat)][c 0..15][plane hi/lo][col 0..383][j 0..7]
__global__ void pack_gru_kernel(const float* __restrict__ Wih, const float* __restrict__ Whh,
                                _Float16* __restrict__ Wp)
{
    int idx = blockIdx.x * 256 + threadIdx.x;
    if (idx >= 2 * NTYPE * 2 * 16 * 384) return;
    int col = idx % 384;
    int c   = (idx / 384) & 15;
    int vm  = idx / 6144;       // (vt*2 + mat), vt = v*6+tt
    int mat = vm & 1;
    int vt  = vm >> 1;
    const float* src = (mat ? Whh : Wih) + ((size_t)vt * 384 + col) * 128 + c * 8;
    float4 u = *(const float4*)src;
    float4 v = *(const float4*)(src + 4);
    float av[8] = {u.x, u.y, u.z, u.w, v.x, v.y, v.z, v.w};
    half8 hh, ll;
    #pragma unroll
    for (int j = 0; j < 8; ++j) { hh[j] = hi_(av[j]); ll[j] = lo_(av[j]); }
    _Float16* dst = Wp + (size_t)vm * 98304 + (size_t)c * 6144;
    *(half8*)(dst + col * 8)        = hh;
    *(half8*)(dst + 3072 + col * 8) = ll;
}

// ---------------------------------------------------------------- MLP + aggregation (split-fp16 MFMA)
// r4 structure (best measured: 150.4 us). bid->(kb,b) mapped so that all 7 kb
// blocks of a given b land on the SAME XCD (XCD k owns b in [16k,16k+16), all
// kb): the 6-way atomicAdd into m_non[b] resolves in one XCD's L2 instead of
// bouncing lines across XCDs.
__global__ __launch_bounds__(512, 4) void mlp_agg_mfma(
    const float* __restrict__ hin, const _Float16* __restrict__ Wp,
    const float* __restrict__ gmat, float* __restrict__ m_non, float* __restrict__ m_uni)
{
    __shared__ _Float16 Xhi[128 * PX];
    __shared__ _Float16 Xlo[128 * PX];

    const int bid = blockIdx.x;
    const int k8 = bid & 7, j = bid >> 3;       // j in 0..111
    const int kb = j >> 4, b = k8 * 16 + (j & 15);
    const int t = threadIdx.x;
    const int wave = t >> 6, lane = t & 63, lo = lane & 31, hi = lane >> 5;
    const int ctw = wave & 3, rh = wave >> 2;   // MLP: col-tile, row-half
    const int wcol = ctw * 32 + lo;             // MLP-phase output column

    // stage layer-0 activations (fp32 -> hi/lo fp16)
    for (int q = t; q < 128 * 32; q += 512) {
        int r = q >> 5, c4 = q & 31;
        float4 v = *(const float4*)(hin + ((size_t)(b * 128 + r)) * 128 + c4 * 4);
        half4 hh, ll;
        hh[0] = hi_(v.x); ll[0] = lo_(v.x);
        hh[1] = hi_(v.y); ll[1] = lo_(v.y);
        hh[2] = hi_(v.z); ll[2] = lo_(v.z);
        hh[3] = hi_(v.w); ll[3] = lo_(v.w);
        *(half4*)(Xhi + r * PX + c4 * 4) = hh;
        *(half4*)(Xlo + r * PX + c4 * 4) = ll;
    }
    __syncthreads();

    floatx16 acc[2];

    #pragma unroll 1
    for (int l = 0; l < NLAY; ++l) {
        #pragma unroll
        for (int r2 = 0; r2 < 2; ++r2) acc[r2] = (floatx16)0.0f;
        const _Float16* wb = Wp + ((size_t)(kb * NLAY + l) * 16) * 2048;

        #pragma unroll
        for (int kk = 0; kk < 8; ++kk) {
            const _Float16* bp = wb + (size_t)(kk * 2 + hi) * 2048;
            half8 b_h = *(const half8*)(bp + wcol * 8);
            half8 b_l = *(const half8*)(bp + 1024 + wcol * 8);
            #pragma unroll
            for (int r2 = 0; r2 < 2; ++r2) {
                int rrow = (rh * 2 + r2) * 32 + lo;
                half8 a_h = *(const half8*)(Xhi + rrow * PX + kk * 16 + hi * 8);
                half8 a_l = *(const half8*)(Xlo + rrow * PX + kk * 16 + hi * 8);
                acc[r2] = __builtin_amdgcn_mfma_f32_32x32x16_f16(a_h, b_h, acc[r2], 0, 0, 0);
                acc[r2] = __builtin_amdgcn_mfma_f32_32x32x16_f16(a_h, b_l, acc[r2], 0, 0, 0);
                acc[r2] = __builtin_amdgcn_mfma_f32_32x32x16_f16(a_l, b_h, acc[r2], 0, 0, 0);
            }
        }
        __syncthreads();   // all waves' X reads for layer l done

        if (l < NLAY - 1) {
            // writeback: fixed column wcol, rows (rh*2+r2)*32+drow
            #pragma unroll
            for (int r2 = 0; r2 < 2; ++r2)
                #pragma unroll
                for (int reg = 0; reg < 16; ++reg) {
                    int n = (rh * 2 + r2) * 32 + drow_(reg, hi);
                    float vv = fmaxf(acc[r2][reg], 0.0f);
                    Xhi[n * PX + wcol] = hi_(vv);
                    Xlo[n * PX + wcol] = lo_(vv);
                }
        } else {
            // final layer: Xt[e][m]; lane's fixed dim IS e=wcol -> contiguous half4 in m
            #pragma unroll
            for (int r2 = 0; r2 < 2; ++r2)
                #pragma unroll
                for (int s = 0; s < 4; ++s) {
                    int m0 = (rh * 2 + r2) * 32 + 8 * s + 4 * hi;
                    half4 hh, ll;
                    #pragma unroll
                    for (int j2 = 0; j2 < 4; ++j2) {
                        float vv = acc[r2][4 * s + j2];
                        hh[j2] = hi_(vv); ll[j2] = lo_(vv);
                    }
                    *(half4*)(Xhi + wcol * PX + m0) = hh;
                    *(half4*)(Xlo + wcol * PX + m0) = ll;
                }
        }
        __syncthreads();
    }

    // ---- aggregation: m[n][d] = sum_m g[b,kb,n,m]*xb[m][d]; A = g (inline split), B = Xt ----
    const int rtw = wave & 3, ch = wave >> 2;
    const int row = rtw * 32 + lo;
    #pragma unroll
    for (int c2 = 0; c2 < 2; ++c2) acc[c2] = (floatx16)0.0f;
    const float* grow = gmat + (size_t)(b * NBOND + kb) * 16384;

    #pragma unroll 2
    for (int kk = 0; kk < 8; ++kk) {
        const float* gp = grow + (size_t)row * 128 + kk * 16 + hi * 8;
        float4 u = *(const float4*)gp, v2 = *(const float4*)(gp + 4);
        float av[8] = {u.x, u.y, u.z, u.w, v2.x, v2.y, v2.z, v2.w};
        half8 a_h, a_l;
        #pragma unroll
        for (int j2 = 0; j2 < 8; ++j2) { a_h[j2] = hi_(av[j2]); a_l[j2] = lo_(av[j2]); }
        #pragma unroll
        for (int c2 = 0; c2 < 2; ++c2) {
            int ct = ch * 2 + c2;
            half8 b_h = *(const half8*)(Xhi + (ct * 32 + lo) * PX + kk * 16 + hi * 8);
            half8 b_l = *(const half8*)(Xlo + (ct * 32 + lo) * PX + kk * 16 + hi * 8);
            acc[c2] = __builtin_amdgcn_mfma_f32_32x32x16_f16(a_h, b_h, acc[c2], 0, 0, 0);
            acc[c2] = __builtin_amdgcn_mfma_f32_32x32x16_f16(a_h, b_l, acc[c2], 0, 0, 0);
            acc[c2] = __builtin_amdgcn_mfma_f32_32x32x16_f16(a_l, b_h, acc[c2], 0, 0, 0);
        }
    }

    if (kb == NBOND - 1) {
        #pragma unroll
        for (int c2 = 0; c2 < 2; ++c2)
            #pragma unroll
            for (int reg = 0; reg < 16; ++reg) {
                int n = rtw * 32 + drow_(reg, hi);
                m_uni[((size_t)(b * 128 + n)) * 128 + (ch * 2 + c2) * 32 + lo] = acc[c2][reg];
            }
    } else {
        #pragma unroll
        for (int c2 = 0; c2 < 2; ++c2)
            #pragma unroll
            for (int reg = 0; reg < 16; ++reg) {
                int n = rtw * 32 + drow_(reg, hi);
                atomicAdd(m_non + ((size_t)(b * 128 + n)) * 128 + (ch * 2 + c2) * 32 + lo,
                          acc[c2][reg]);
            }
    }
}

// ---------------------------------------------------------------- grouped GRU (split-fp16 MFMA)
// 64-node slices x v-split grid: block = (desc slice, v = blockIdx.y).
// ~516 active blocks -> 2 blocks/CU (LDS 69.6 KB), 2 waves/SIMD (r8's TLP),
// AND per-block weight fragments reused in registers by two 32-row groups
// (r9's halved weight traffic: ~198 MB/dispatch), AND serial chain is half of
// r9's (one v per block). Outputs combine via atomicAdd into zeroed hout
// (h ping-pongs ws <-> d_out across passes).
__global__ __launch_bounds__(256, 2) void gru_mfma(
    const float* __restrict__ hin, float* __restrict__ hout,
    const float* __restrict__ m_non, const float* __restrict__ m_uni,
    const int* __restrict__ counts, const int* __restrict__ bucket,
    const int* __restrict__ desc,
    const _Float16* __restrict__ Wp, const float* __restrict__ bihp, const float* __restrict__ bhhp)
{
    __shared__ _Float16 Xh[64 * PX], Xl[64 * PX], Mh[64 * PX], Ml[64 * PX];
    __shared__ int bl[64];

    const int bid = blockIdx.x;
    const int dv = desc[(bid & 7) * (NDESC / 8) + (bid >> 3)];
    if (dv < 0) return;
    const int tt = dv & 7;
    const int v = blockIdx.y;
    const int base = (dv >> 3) * 64;
    const int t = threadIdx.x;
    const int cnt = counts[tt];
    const int nn = min(64, cnt - base);
    if (t < 64) bl[t] = (t < nn) ? bucket[tt * NNODES + base + t] : -1;
    __syncthreads();

    const float* msrc = v ? m_uni : m_non;

    // stage X and M together (64 gathered rows, split fp16, zero-fill inactive)
    for (int q = t; q < 64 * 32; q += 256) {
        int r = q >> 5, c4 = q & 31;
        float4 xv = make_float4(0.f, 0.f, 0.f, 0.f);
        float4 mv = make_float4(0.f, 0.f, 0.f, 0.f);
        int node = bl[r];
        if (node >= 0) {
            xv = *(const float4*)(hin  + (size_t)node * 128 + c4 * 4);
            mv = *(const float4*)(msrc + (size_t)node * 128 + c4 * 4);
        }
        half4 hh, ll;
        hh[0] = hi_(xv.x); ll[0] = lo_(xv.x);
        hh[1] = hi_(xv.y); ll[1] = lo_(xv.y);
        hh[2] = hi_(xv.z); ll[2] = lo_(xv.z);
        hh[3] = hi_(xv.w); ll[3] = lo_(xv.w);
        *(half4*)(Xh + r * PX + c4 * 4) = hh;
        *(half4*)(Xl + r * PX + c4 * 4) = ll;
        hh[0] = hi_(mv.x); ll[0] = lo_(mv.x);
        hh[1] = hi_(mv.y); ll[1] = lo_(mv.y);
        hh[2] = hi_(mv.z); ll[2] = lo_(mv.z);
        hh[3] = hi_(mv.w); ll[3] = lo_(mv.w);
        *(half4*)(Mh + r * PX + c4 * 4) = hh;
        *(half4*)(Ml + r * PX + c4 * 4) = ll;
    }
    __syncthreads();

    const int wave = t >> 6, lane = t & 63, lo = lane & 31, hi = lane >> 5;
    const int d = wave * 32 + lo;
    const int vt = v * NTYPE + tt;
    const _Float16* pih = Wp + (size_t)(vt * 2 + 0) * 98304;
    const _Float16* phh = Wp + (size_t)(vt * 2 + 1) * 98304;

    floatx16 ar[2], az[2], ax[2], ah[2];
    #pragma unroll
    for (int r2 = 0; r2 < 2; ++r2) {
        ar[r2] = (floatx16)0.0f; az[r2] = (floatx16)0.0f;
        ax[r2] = (floatx16)0.0f; ah[r2] = (floatx16)0.0f;
    }

    #pragma unroll 2
    for (int kk = 0; kk < 8; ++kk) {
        int koff = kk * 16 + hi * 8;
        half8 xh[2], xl[2], mh[2], ml[2];
        #pragma unroll
        for (int r2 = 0; r2 < 2; ++r2) {
            int rr = r2 * 32 + lo;
            xh[r2] = *(const half8*)(Xh + rr * PX + koff);
            xl[r2] = *(const half8*)(Xl + rr * PX + koff);
            mh[r2] = *(const half8*)(Mh + rr * PX + koff);
            ml[r2] = *(const half8*)(Ml + rr * PX + koff);
        }
        const _Float16* ci = pih + (size_t)(kk * 2 + hi) * 6144;
        const _Float16* ch = phh + (size_t)(kk * 2 + hi) * 6144;

        {   // r gate, input side
            half8 wh = *(const half8*)(ci + (0 + d) * 8);
            half8 wl = *(const half8*)(ci + 3072 + (0 + d) * 8);
            #pragma unroll
            for (int r2 = 0; r2 < 2; ++r2) {
                ar[r2] = __builtin_amdgcn_mfma_f32_32x32x16_f16(xh[r2], wh, ar[r2], 0, 0, 0);
                ar[r2] = __builtin_amdgcn_mfma_f32_32x32x16_f16(xh[r2], wl, ar[r2], 0, 0, 0);
                ar[r2] = __builtin_amdgcn_mfma_f32_32x32x16_f16(xl[r2], wh, ar[r2], 0, 0, 0);
            }
        }
        {   // r gate, hidden side
            half8 wh = *(const half8*)(ch + (0 + d) * 8);
            half8 wl = *(const half8*)(ch + 3072 + (0 + d) * 8);
            #pragma unroll
            for (int r2 = 0; r2 < 2; ++r2) {
                ar[r2] = __builtin_amdgcn_mfma_f32_32x32x16_f16(mh[r2], wh, ar[r2], 0, 0, 0);
                ar[r2] = __builtin_amdgcn_mfma_f32_32x32x16_f16(mh[r2], wl, ar[r2], 0, 0, 0);
                ar[r2] = __builtin_amdgcn_mfma_f32_32x32x16_f16(ml[r2], wh, ar[r2], 0, 0, 0);
            }
        }
        {   // z gate, input side
            half8 wh = *(const half8*)(ci + (128 + d) * 8);
            half8 wl = *(const half8*)(ci + 3072 + (128 + d) * 8);
            #pragma unroll
            for (int r2 = 0; r2 < 2; ++r2) {
                az[r2] = __builtin_amdgcn_mfma_f32_32x32x16_f16(xh[r2], wh, az[r2], 0, 0, 0);
                az[r2] = __builtin_amdgcn_mfma_f32_32x32x16_f16(xh[r2], wl, az[r2], 0, 0, 0);
                az[r2] = __builtin_amdgcn_mfma_f32_32x32x16_f16(xl[r2], wh, az[r2], 0, 0, 0);
            }
        }
        {   // z gate, hidden side
            half8 wh = *(const half8*)(ch + (128 + d) * 8);
            half8 wl = *(const half8*)(ch + 3072 + (128 + d) * 8);
            #pragma unroll
            for (int r2 = 0; r2 < 2; ++r2) {
                az[r2] = __builtin_amdgcn_mfma_f32_32x32x16_f16(mh[r2], wh, az[r2], 0, 0, 0);
                az[r2] = __builtin_amdgcn_mfma_f32_32x32x16_f16(mh[r2], wl, az[r2], 0, 0, 0);
                az[r2] = __builtin_amdgcn_mfma_f32_32x32x16_f16(ml[r2], wh, az[r2], 0, 0, 0);
            }
        }
        {   // n gate, input side (ax)
            half8 wh = *(const half8*)(ci + (256 + d) * 8);
            half8 wl = *(const half8*)(ci + 3072 + (256 + d) * 8);
            #pragma unroll
            for (int r2 = 0; r2 < 2; ++r2) {
                ax[r2] = __builtin_amdgcn_mfma_f32_32x32x16_f16(xh[r2], wh, ax[r2], 0, 0, 0);
                ax[r2] = __builtin_amdgcn_mfma_f32_32x32x16_f16(xh[r2], wl, ax[r2], 0, 0, 0);
                ax[r2] = __builtin_amdgcn_mfma_f32_32x32x16_f16(xl[r2], wh, ax[r2], 0, 0, 0);
            }
        }
        {   // n gate, hidden side (ah)
            half8 wh = *(const half8*)(ch + (256 + d) * 8);
            half8 wl = *(const half8*)(ch + 3072 + (256 + d) * 8);
            #pragma unroll
            for (int r2 = 0; r2 < 2; ++r2) {
                ah[r2] = __builtin_amdgcn_mfma_f32_32x32x16_f16(mh[r2], wh, ah[r2], 0, 0, 0);
                ah[r2] = __builtin_amdgcn_mfma_f32_32x32x16_f16(mh[r2], wl, ah[r2], 0, 0, 0);
                ah[r2] = __builtin_amdgcn_mfma_f32_32x32x16_f16(ml[r2], wh, ah[r2], 0, 0, 0);
            }
        }
    }

    const float* bi = bihp + (size_t)vt * 384;
    const float* bh = bhhp + (size_t)vt * 384;
    float b_r  = bi[d] + bh[d];
    float b_z  = bi[128 + d] + bh[128 + d];
    float b_in = bi[256 + d];
    float b_hn = bh[256 + d];
    #pragma unroll
    for (int r2 = 0; r2 < 2; ++r2)
        #pragma unroll
        for (int reg = 0; reg < 16; ++reg) {
            int n = r2 * 32 + drow_(reg, hi);
            int node = bl[n];
            if (node < 0) continue;
            float r  = sig_(ar[r2][reg] + b_r);
            float z  = sig_(az[r2][reg] + b_z);
            float nv = tanhf(ax[r2][reg] + b_in + r * (ah[r2][reg] + b_hn));
            float mv = msrc[(size_t)node * 128 + d];   // fp32 m for z*m
            atomicAdd(hout + (size_t)node * 128 + d, (1.0f - z) * nv + z * mv);
        }
}

// ---------------------------------------------------------------- launch
extern "C" void kernel_launch(void* const* d_in, const int* in_sizes, int n_in,
                              void* d_out, int out_size, void* d_ws, size_t ws_size,
                              hipStream_t stream) {
    const float* g    = (const float*)d_in[0];
    const float* h    = (const float*)d_in[1];
    const float* msgW = (const float*)d_in[2];
    const float* Wih  = (const float*)d_in[3];
    const float* Whh  = (const float*)d_in[4];
    const float* bih  = (const float*)d_in[5];
    const float* bhh  = (const float*)d_in[6];
    float* h1 = (float*)d_out;

    char* ws = (char*)d_ws;
    float* m_non = (float*)ws;                                   // 8 MB
    float* m_uni = m_non + (size_t)NNODES * 128;                 // 8 MB
    int* counts  = (int*)(ws + 2 * (size_t)NNODES * 128 * 4);
    int* bucket  = counts + 8;                                   // [6][16384]
    int* desc    = bucket + NTYPE * NNODES;                      // [264]
    _Float16* WpM = (_Float16*)(desc + NDESC);                   // 1,835,008 halves (3.67 MB)
    _Float16* WpG = WpM + (size_t)NBOND * NLAY * 16 * 2048;      // 2,359,296 halves (4.72 MB)
    float* h0 = (float*)(WpG + (size_t)2 * NTYPE * 2 * 98304);   // 8 MB ping-pong h buffer

    (void)hipMemsetAsync(counts, 0, 8 * sizeof(int), stream);
    setup_kernel<<<NNODES * 128 / 256, 256, 0, stream>>>(h, h0, counts, bucket);
    build_desc_kernel<<<1, 64, 0, stream>>>(counts, desc);
    pack_msg_kernel<<<(NBOND * NLAY * 16 * 128 + 255) / 256, 256, 0, stream>>>(msgW, WpM);
    pack_gru_kernel<<<(2 * NTYPE * 2 * 16 * 384 + 255) / 256, 256, 0, stream>>>(Wih, Whh, WpG);

    // h ping-pong: p0 h0->h1(d_out), p1 h1->h0, p2 h0->h1(d_out)
    const float* hin_p[3]  = {h0, h1, h0};
    float*       hout_p[3] = {h1, h0, h1};
    for (int pass = 0; pass < 3; ++pass) {
        (void)hipMemsetAsync(m_non, 0, (size_t)NNODES * 128 * 4, stream);
        (void)hipMemsetAsync(hout_p[pass], 0, (size_t)NNODES * 128 * 4, stream);
        mlp_agg_mfma<<<dim3(NBOND * 128), 512, 0, stream>>>(hin_p[pass], WpM, g, m_non, m_uni);
        gru_mfma<<<dim3(NDESC, 2), 256, 0, stream>>>(hin_p[pass], hout_p[pass], m_non, m_uni,
                                                     counts, bucket, desc, WpG, bih, bhh);
    }
}

// Round 11
// 855.729 us; speedup vs baseline: 1.0291x; 1.0291x over previous
//
#include <hip/hip_runtime.h>
#include <math.h>

#define NBOND 7
#define NLAY 8
#define NTYPE 6
#define NNODES 16384   // B*N = 128*128
#define PX 136         // LDS pitch in halves (272 B, 16B-aligned; 68 dw % 32 = 4 -> conflict-clean)
#define NDESC 520      // 8 XCDs x 65 desc slots (>= 518 max active 32-node slices)

typedef _Float16 half8 __attribute__((ext_vector_type(8)));
typedef _Float16 half4 __attribute__((ext_vector_type(4)));
typedef float floatx16 __attribute__((ext_vector_type(16)));

__device__ __forceinline__ float sig_(float x) { return 1.0f / (1.0f + __expf(-x)); }
// D-layout for 32x32 MFMA: col = lane&31, row = (reg&3) + 8*(reg>>2) + 4*(lane>>5)
__device__ __forceinline__ int drow_(int reg, int hi) { return (reg & 3) + 8 * (reg >> 2) + 4 * hi; }

__device__ __forceinline__ _Float16 hi_(float v) { return (_Float16)v; }
__device__ __forceinline__ _Float16 lo_(float v) { return (_Float16)(v - (float)(_Float16)v); }

// asm loads: cannot be sunk, coalesced, or rotated by the compiler (r2/r5 failure modes).
// No implicit waitcnt — consumer must asm-wait vmcnt before use.
__device__ __forceinline__ void ldg128(half8& d, const _Float16* p) {
    asm volatile("global_load_dwordx4 %0, %1, off" : "=v"(d) : "v"(p) : "memory");
}
__device__ __forceinline__ void ldg128_o2048(half8& d, const _Float16* p) {
    asm volatile("global_load_dwordx4 %0, %1, off offset:2048" : "=v"(d) : "v"(p) : "memory");
}

// ---------------------------------------------------------------- setup
__global__ void setup_kernel(const float* __restrict__ h, float* __restrict__ hT,
                             int* __restrict__ counts, int* __restrict__ bucket)
{
    int gid = blockIdx.x * 256 + threadIdx.x;
    int node = gid >> 7, d = gid & 127;
    hT[gid] = (d < 75) ? h[node * 75 + d] : 0.0f;
    if (gid < NNODES) {
        float a = h[gid * 75];
        int tt = 5;
        if      (a == 6.0f) tt = 0;
        else if (a == 7.0f) tt = 1;
        else if (a == 8.0f) tt = 2;
        else if (a == 9.0f) tt = 3;
        else if (a == 0.0f) tt = 4;
        int slot = atomicAdd(&counts[tt], 1);
        bucket[tt * NNODES + slot] = gid;
    }
}

// Dense GRU block descriptors over 32-node slices (r8 form): desc[i] = tt | (slice<<3).
__global__ void build_desc_kernel(const int* __restrict__ counts, int* __restrict__ desc)
{
    if (threadIdx.x != 0 || blockIdx.x != 0) return;
    int i = 0;
    for (int tt = 0; tt < NTYPE; ++tt) {
        int nb = (counts[tt] + 31) >> 5;
        for (int s = 0; s < nb; ++s) desc[i++] = tt | (s << 3);
    }
    while (i < NDESC) desc[i++] = -1;
}

// ---------------------------------------------------------------- weight packing (fp32 -> split fp16 hi/lo planes)
// msgW: [(kb*8+l)][c 0..15][plane hi/lo][e 0..127][j 0..7]  (j along input dim d)
__global__ void pack_msg_kernel(const float* __restrict__ msgW, _Float16* __restrict__ Wp)
{
    int idx = blockIdx.x * 256 + threadIdx.x;
    if (idx >= NBOND * NLAY * 16 * 128) return;
    int e  = idx & 127;
    int c  = (idx >> 7) & 15;
    int kl = idx >> 11;
    const float* src = msgW + ((size_t)kl * 128 + e) * 128 + c * 8;
    float4 u = *(const float4*)src;
    float4 v = *(const float4*)(src + 4);
    float av[8] = {u.x, u.y, u.z, u.w, v.x, v.y, v.z, v.w};
    half8 hh, ll;
    #pragma unroll
    for (int j = 0; j < 8; ++j) { hh[j] = hi_(av[j]); ll[j] = lo_(av[j]); }
    _Float16* dst = Wp + ((size_t)kl * 16 + c) * 2048;
    *(half8*)(dst + e * 8)        = hh;
    *(half8*)(dst + 1024 + e * 8) = ll;
}

// GRU: [(vt*2+mat)][c 0..15][plane hi/lo][col 0..383][j 0..7]
__global__ void pack_gru_kernel(const float* __restrict__ Wih, const float* __restrict__ Whh,
                                _Float16* __restrict__ Wp)
{
    int idx = blockIdx.x * 256 + threadIdx.x;
    if (idx >= 2 * NTYPE * 2 * 16 * 384) return;
    int col = idx % 384;
    int c   = (idx / 384) & 15;
    int vm  = idx / 6144;       // (vt*2 + mat), vt = v*6+tt
    int mat = vm & 1;
    int vt  = vm >> 1;
    const float* src = (mat ? Whh : Wih) + ((size_t)vt * 384 + col) * 128 + c * 8;
    float4 u = *(const float4*)src;
    float4 v = *(const float4*)(src + 4);
    float av[8] = {u.x, u.y, u.z, u.w, v.x, v.y, v.z, v.w};
    half8 hh, ll;
    #pragma unroll
    for (int j = 0; j < 8; ++j) { hh[j] = hi_(av[j]); ll[j] = lo_(av[j]); }
    _Float16* dst = Wp + (size_t)vm * 98304 + (size_t)c * 6144;
    *(half8*)(dst + col * 8)        = hh;
    *(half8*)(dst + 3072 + col * 8) = ll;
}

// ---------------------------------------------------------------- MLP + aggregation (split-fp16 MFMA)
// r4/r8 tile structure, but the 16 per-wave weight fragments of layer l+1 are
// prefetched into REGISTERS via inline-asm global_load_dwordx4 at layer l's
// tail. asm volatile loads can't be sunk (r2) and launch_bounds(512,2) gives a
// 256-VGPR budget (r5's spill). Raw s_barrier (no vmcnt drain) lets the
// prefetch ride across the inter-layer barriers (r5's proven scheme); one
// asm vmcnt(0) at the next layer head collapses the 16 serial L2 round-trips
// per layer (the measured ~22k cy/layer stall) into one.
__global__ __launch_bounds__(512, 2) void mlp_agg_mfma(
    const float* __restrict__ hin, const _Float16* __restrict__ Wp,
    const float* __restrict__ gmat, float* __restrict__ m_non, float* __restrict__ m_uni)
{
    __shared__ _Float16 Xhi[128 * PX];
    __shared__ _Float16 Xlo[128 * PX];

    const int t = threadIdx.x;
    const int kb = blockIdx.x, b = blockIdx.y;
    const int wave = t >> 6, lane = t & 63, lo = lane & 31, hi = lane >> 5;
    const int ctw = wave & 3, rh = wave >> 2;   // MLP: col-tile, row-half
    const int wcol = ctw * 32 + lo;             // MLP-phase output column

    half8 Wh[8], Wl[8];

    // prologue: issue layer-0 weight loads; latency overlaps the X staging.
    {
        const _Float16* wb0 = Wp + ((size_t)(kb * NLAY) * 16) * 2048;
        #pragma unroll
        for (int kk = 0; kk < 8; ++kk) {
            const _Float16* bp = wb0 + (size_t)(kk * 2 + hi) * 2048 + wcol * 8;
            ldg128(Wh[kk], bp);
            ldg128_o2048(Wl[kk], bp);
        }
    }

    // stage layer-0 activations (fp32 -> hi/lo fp16)
    for (int q = t; q < 128 * 32; q += 512) {
        int r = q >> 5, c4 = q & 31;
        float4 v = *(const float4*)(hin + ((size_t)(b * 128 + r)) * 128 + c4 * 4);
        half4 hh, ll;
        hh[0] = hi_(v.x); ll[0] = lo_(v.x);
        hh[1] = hi_(v.y); ll[1] = lo_(v.y);
        hh[2] = hi_(v.z); ll[2] = lo_(v.z);
        hh[3] = hi_(v.w); ll[3] = lo_(v.w);
        *(half4*)(Xhi + r * PX + c4 * 4) = hh;
        *(half4*)(Xlo + r * PX + c4 * 4) = ll;
    }
    __syncthreads();   // drains vmcnt(0): X + layer-0 W landed. Fine once.

    floatx16 acc[2];

    #pragma unroll 1
    for (int l = 0; l < NLAY; ++l) {
        // W fragments for this layer are in flight (or landed): wait once.
        asm volatile("s_waitcnt vmcnt(0)" ::: "memory");
        __builtin_amdgcn_sched_barrier(0);

        #pragma unroll
        for (int r2 = 0; r2 < 2; ++r2) acc[r2] = (floatx16)0.0f;

        #pragma unroll
        for (int kk = 0; kk < 8; ++kk) {
            #pragma unroll
            for (int r2 = 0; r2 < 2; ++r2) {
                int rrow = (rh * 2 + r2) * 32 + lo;
                half8 a_h = *(const half8*)(Xhi + rrow * PX + kk * 16 + hi * 8);
                half8 a_l = *(const half8*)(Xlo + rrow * PX + kk * 16 + hi * 8);
                acc[r2] = __builtin_amdgcn_mfma_f32_32x32x16_f16(a_h, Wh[kk], acc[r2], 0, 0, 0);
                acc[r2] = __builtin_amdgcn_mfma_f32_32x32x16_f16(a_h, Wl[kk], acc[r2], 0, 0, 0);
                acc[r2] = __builtin_amdgcn_mfma_f32_32x32x16_f16(a_l, Wh[kk], acc[r2], 0, 0, 0);
            }
        }

        // W regs dead: issue next layer's 16 fragment loads (asm, un-sinkable).
        if (l < NLAY - 1) {
            const _Float16* wbn = Wp + ((size_t)(kb * NLAY + l + 1) * 16) * 2048;
            #pragma unroll
            for (int kk = 0; kk < 8; ++kk) {
                const _Float16* bp = wbn + (size_t)(kk * 2 + hi) * 2048 + wcol * 8;
                ldg128(Wh[kk], bp);
                ldg128_o2048(Wl[kk], bp);
            }
        }
        __builtin_amdgcn_sched_barrier(0);

        // barrier 1: all waves' X reads done (ds_reads drained at MFMA use).
        // Raw s_barrier: no vmcnt drain -> prefetch stays in flight.
        asm volatile("" ::: "memory");
        __builtin_amdgcn_s_barrier();

        if (l < NLAY - 1) {
            // writeback: fixed column wcol, rows (rh*2+r2)*32+drow
            #pragma unroll
            for (int r2 = 0; r2 < 2; ++r2)
                #pragma unroll
                for (int reg = 0; reg < 16; ++reg) {
                    int n = (rh * 2 + r2) * 32 + drow_(reg, hi);
                    float vv = fmaxf(acc[r2][reg], 0.0f);
                    Xhi[n * PX + wcol] = hi_(vv);
                    Xlo[n * PX + wcol] = lo_(vv);
                }
        } else {
            // final layer: Xt[e][m]; lane's fixed dim IS e=wcol -> contiguous half4 in m
            #pragma unroll
            for (int r2 = 0; r2 < 2; ++r2)
                #pragma unroll
                for (int s = 0; s < 4; ++s) {
                    int m0 = (rh * 2 + r2) * 32 + 8 * s + 4 * hi;
                    half4 hh, ll;
                    #pragma unroll
                    for (int j = 0; j < 4; ++j) {
                        float vv = acc[r2][4 * s + j];
                        hh[j] = hi_(vv); ll[j] = lo_(vv);
                    }
                    *(half4*)(Xhi + wcol * PX + m0) = hh;
                    *(half4*)(Xlo + wcol * PX + m0) = ll;
                }
        }

        // barrier 2: LDS writes visible -> lgkmcnt(0) only (no vmcnt drain).
        asm volatile("s_waitcnt lgkmcnt(0)" ::: "memory");
        __builtin_amdgcn_s_barrier();
        asm volatile("" ::: "memory");
    }

    // ---- aggregation: m[n][d] = sum_m g[b,kb,n,m]*xb[m][d]; A = g (inline split), B = Xt ----
    const int rtw = wave & 3, ch = wave >> 2;
    const int row = rtw * 32 + lo;
    #pragma unroll
    for (int c2 = 0; c2 < 2; ++c2) acc[c2] = (floatx16)0.0f;
    const float* grow = gmat + (size_t)(b * NBOND + kb) * 16384;

    #pragma unroll 2
    for (int kk = 0; kk < 8; ++kk) {
        const float* gp = grow + (size_t)row * 128 + kk * 16 + hi * 8;
        float4 u = *(const float4*)gp, v2 = *(const float4*)(gp + 4);
        float av[8] = {u.x, u.y, u.z, u.w, v2.x, v2.y, v2.z, v2.w};
        half8 a_h, a_l;
        #pragma unroll
        for (int j = 0; j < 8; ++j) { a_h[j] = hi_(av[j]); a_l[j] = lo_(av[j]); }
        #pragma unroll
        for (int c2 = 0; c2 < 2; ++c2) {
            int ct = ch * 2 + c2;
            half8 b_h = *(const half8*)(Xhi + (ct * 32 + lo) * PX + kk * 16 + hi * 8);
            half8 b_l = *(const half8*)(Xlo + (ct * 32 + lo) * PX + kk * 16 + hi * 8);
            acc[c2] = __builtin_amdgcn_mfma_f32_32x32x16_f16(a_h, b_h, acc[c2], 0, 0, 0);
            acc[c2] = __builtin_amdgcn_mfma_f32_32x32x16_f16(a_h, b_l, acc[c2], 0, 0, 0);
            acc[c2] = __builtin_amdgcn_mfma_f32_32x32x16_f16(a_l, b_h, acc[c2], 0, 0, 0);
        }
    }

    if (kb == NBOND - 1) {
        #pragma unroll
        for (int c2 = 0; c2 < 2; ++c2)
            #pragma unroll
            for (int reg = 0; reg < 16; ++reg) {
                int n = rtw * 32 + drow_(reg, hi);
                m_uni[((size_t)(b * 128 + n)) * 128 + (ch * 2 + c2) * 32 + lo] = acc[c2][reg];
            }
    } else {
        #pragma unroll
        for (int c2 = 0; c2 < 2; ++c2)
            #pragma unroll
            for (int reg = 0; reg < 16; ++reg) {
                int n = rtw * 32 + drow_(reg, hi);
                atomicAdd(m_non + ((size_t)(b * 128 + n)) * 128 + (ch * 2 + c2) * 32 + lo,
                          acc[c2][reg]);
            }
    }
}

// ---------------------------------------------------------------- grouped GRU (split-fp16 MFMA) — r8 exact (best measured)
// Dense grid of NDESC blocks; block -> (tt, slice) via desc with XCD-chunked
// mapping. One block = 32 gathered nodes of one type, BOTH GRU variants
// (v-loop, M restaged per v). LDS 35 KB -> 4 blocks/CU. Block owns its nodes
// exclusively -> in-place hT update: v=0 stores, v=1 read-add-stores.
__global__ __launch_bounds__(256, 3) void gru_mfma(
    float* __restrict__ hT,
    const float* __restrict__ m_non, const float* __restrict__ m_uni,
    const int* __restrict__ counts, const int* __restrict__ bucket,
    const int* __restrict__ desc,
    const _Float16* __restrict__ Wp, const float* __restrict__ bihp, const float* __restrict__ bhhp)
{
    __shared__ _Float16 Xh[32 * PX], Xl[32 * PX], Mh[32 * PX], Ml[32 * PX];
    __shared__ int bl[32];

    const int bid = blockIdx.x;
    const int dv = desc[(bid & 7) * (NDESC / 8) + (bid >> 3)];
    if (dv < 0) return;
    const int tt = dv & 7;
    const int base = (dv >> 3) * 32;
    const int t = threadIdx.x;
    const int cnt = counts[tt];
    const int nn = min(32, cnt - base);
    if (t < 32) bl[t] = (t < nn) ? bucket[tt * NNODES + base + t] : -1;
    __syncthreads();

    // stage X once (gathered h rows, split fp16, zero-fill inactive)
    for (int q = t; q < 32 * 32; q += 256) {
        int r = q >> 5, c4 = q & 31;
        float4 xv = make_float4(0.f, 0.f, 0.f, 0.f);
        int node = bl[r];
        if (node >= 0) xv = *(const float4*)(hT + (size_t)node * 128 + c4 * 4);
        half4 hh, ll;
        hh[0] = hi_(xv.x); ll[0] = lo_(xv.x);
        hh[1] = hi_(xv.y); ll[1] = lo_(xv.y);
        hh[2] = hi_(xv.z); ll[2] = lo_(xv.z);
        hh[3] = hi_(xv.w); ll[3] = lo_(xv.w);
        *(half4*)(Xh + r * PX + c4 * 4) = hh;
        *(half4*)(Xl + r * PX + c4 * 4) = ll;
    }

    const int wave = t >> 6, lane = t & 63, lo = lane & 31, hi = lane >> 5;
    const int d = wave * 32 + lo;

    #pragma unroll 1
    for (int v = 0; v < 2; ++v) {
        const float* msrc = v ? m_uni : m_non;
        __syncthreads();   // v=0: X-stage commit; v=1: prior M readers done
        for (int q = t; q < 32 * 32; q += 256) {
            int r = q >> 5, c4 = q & 31;
            float4 mv = make_float4(0.f, 0.f, 0.f, 0.f);
            int node = bl[r];
            if (node >= 0) mv = *(const float4*)(msrc + (size_t)node * 128 + c4 * 4);
            half4 hh, ll;
            hh[0] = hi_(mv.x); ll[0] = lo_(mv.x);
            hh[1] = hi_(mv.y); ll[1] = lo_(mv.y);
            hh[2] = hi_(mv.z); ll[2] = lo_(mv.z);
            hh[3] = hi_(mv.w); ll[3] = lo_(mv.w);
            *(half4*)(Mh + r * PX + c4 * 4) = hh;
            *(half4*)(Ml + r * PX + c4 * 4) = ll;
        }
        __syncthreads();

        const int vt = v * NTYPE + tt;
        const _Float16* pih = Wp + (size_t)(vt * 2 + 0) * 98304;
        const _Float16* phh = Wp + (size_t)(vt * 2 + 1) * 98304;

        floatx16 ar = (floatx16)0.0f, az = (floatx16)0.0f;
        floatx16 ax = (floatx16)0.0f, ah = (floatx16)0.0f;

        #pragma unroll 2
        for (int kk = 0; kk < 8; ++kk) {
            int koff = kk * 16 + hi * 8;
            half8 xh = *(const half8*)(Xh + lo * PX + koff);
            half8 xl = *(const half8*)(Xl + lo * PX + koff);
            half8 mh = *(const half8*)(Mh + lo * PX + koff);
            half8 ml = *(const half8*)(Ml + lo * PX + koff);
            const _Float16* ci = pih + (size_t)(kk * 2 + hi) * 6144;
            const _Float16* ch = phh + (size_t)(kk * 2 + hi) * 6144;
            half8 birh = *(const half8*)(ci + (0   + d) * 8);
            half8 birl = *(const half8*)(ci + 3072 + (0   + d) * 8);
            half8 bizh = *(const half8*)(ci + (128 + d) * 8);
            half8 bizl = *(const half8*)(ci + 3072 + (128 + d) * 8);
            half8 binh = *(const half8*)(ci + (256 + d) * 8);
            half8 binl = *(const half8*)(ci + 3072 + (256 + d) * 8);
            half8 bhrh = *(const half8*)(ch + (0   + d) * 8);
            half8 bhrl = *(const half8*)(ch + 3072 + (0   + d) * 8);
            half8 bhzh = *(const half8*)(ch + (128 + d) * 8);
            half8 bhzl = *(const half8*)(ch + 3072 + (128 + d) * 8);
            half8 bhnh = *(const half8*)(ch + (256 + d) * 8);
            half8 bhnl = *(const half8*)(ch + 3072 + (256 + d) * 8);

            ar = __builtin_amdgcn_mfma_f32_32x32x16_f16(xh, birh, ar, 0, 0, 0);
            ar = __builtin_amdgcn_mfma_f32_32x32x16_f16(xh, birl, ar, 0, 0, 0);
            ar = __builtin_amdgcn_mfma_f32_32x32x16_f16(xl, birh, ar, 0, 0, 0);
            ar = __builtin_amdgcn_mfma_f32_32x32x16_f16(mh, bhrh, ar, 0, 0, 0);
            ar = __builtin_amdgcn_mfma_f32_32x32x16_f16(mh, bhrl, ar, 0, 0, 0);
            ar = __builtin_amdgcn_mfma_f32_32x32x16_f16(ml, bhrh, ar, 0, 0, 0);

            az = __builtin_amdgcn_mfma_f32_32x32x16_f16(xh, bizh, az, 0, 0, 0);
            az = __builtin_amdgcn_mfma_f32_32x32x16_f16(xh, bizl, az, 0, 0, 0);
            az = __builtin_amdgcn_mfma_f32_32x32x16_f16(xl, bizh, az, 0, 0, 0);
            az = __builtin_amdgcn_mfma_f32_32x32x16_f16(mh, bhzh, az, 0, 0, 0);
            az = __builtin_amdgcn_mfma_f32_32x32x16_f16(mh, bhzl, az, 0, 0, 0);
            az = __builtin_amdgcn_mfma_f32_32x32x16_f16(ml, bhzh, az, 0, 0, 0);

            ax = __builtin_amdgcn_mfma_f32_32x32x16_f16(xh, binh, ax, 0, 0, 0);
            ax = __builtin_amdgcn_mfma_f32_32x32x16_f16(xh, binl, ax, 0, 0, 0);
            ax = __builtin_amdgcn_mfma_f32_32x32x16_f16(xl, binh, ax, 0, 0, 0);
            ah = __builtin_amdgcn_mfma_f32_32x32x16_f16(mh, bhnh, ah, 0, 0, 0);
            ah = __builtin_amdgcn_mfma_f32_32x32x16_f16(mh, bhnl, ah, 0, 0, 0);
            ah = __builtin_amdgcn_mfma_f32_32x32x16_f16(ml, bhnh, ah, 0, 0, 0);
        }

        const float* bi = bihp + (size_t)vt * 384;
        const float* bh = bhhp + (size_t)vt * 384;
        float b_r  = bi[d] + bh[d];
        float b_z  = bi[128 + d] + bh[128 + d];
        float b_in = bi[256 + d];
        float b_hn = bh[256 + d];
        #pragma unroll
        for (int reg = 0; reg < 16; ++reg) {
            int n = drow_(reg, hi);
            int node = bl[n];
            if (node < 0) continue;
            float r  = sig_(ar[reg] + b_r);
            float z  = sig_(az[reg] + b_z);
            float nv = tanhf(ax[reg] + b_in + r * (ah[reg] + b_hn));
            float mv = msrc[(size_t)node * 128 + d];   // fp32 m for z*m
            float val = (1.0f - z) * nv + z * mv;
            if (v == 0) hT[(size_t)node * 128 + d] = val;                       // overwrite old h
            else        hT[(size_t)node * 128 + d] += val;                      // block owns node
        }
    }
}

// ---------------------------------------------------------------- launch
extern "C" void kernel_launch(void* const* d_in, const int* in_sizes, int n_in,
                              void* d_out, int out_size, void* d_ws, size_t ws_size,
                              hipStream_t stream) {
    const float* g    = (const float*)d_in[0];
    const float* h    = (const float*)d_in[1];
    const float* msgW = (const float*)d_in[2];
    const float* Wih  = (const float*)d_in[3];
    const float* Whh  = (const float*)d_in[4];
    const float* bih  = (const float*)d_in[5];
    const float* bhh  = (const float*)d_in[6];
    float* hT = (float*)d_out;

    char* ws = (char*)d_ws;
    float* m_non = (float*)ws;                                   // 8 MB
    float* m_uni = m_non + (size_t)NNODES * 128;                 // 8 MB
    int* counts  = (int*)(ws + 2 * (size_t)NNODES * 128 * 4);
    int* bucket  = counts + 8;                                   // [6][16384]
    int* desc    = bucket + NTYPE * NNODES;                      // [520]
    _Float16* WpM = (_Float16*)(desc + NDESC);                   // 1,835,008 halves (3.67 MB)
    _Float16* WpG = WpM + (size_t)NBOND * NLAY * 16 * 2048;      // 2,359,296 halves (4.72 MB)

    (void)hipMemsetAsync(counts, 0, 8 * sizeof(int), stream);
    setup_kernel<<<NNODES * 128 / 256, 256, 0, stream>>>(h, hT, counts, bucket);
    build_desc_kernel<<<1, 64, 0, stream>>>(counts, desc);
    pack_msg_kernel<<<(NBOND * NLAY * 16 * 128 + 255) / 256, 256, 0, stream>>>(msgW, WpM);
    pack_gru_kernel<<<(2 * NTYPE * 2 * 16 * 384 + 255) / 256, 256, 0, stream>>>(Wih, Whh, WpG);

    for (int pass = 0; pass < 3; ++pass) {
        (void)hipMemsetAsync(m_non, 0, (size_t)NNODES * 128 * 4, stream);
        mlp_agg_mfma<<<dim3(NBOND, 128), 512, 0, stream>>>(hT, WpM, g, m_non, m_uni);
        gru_mfma<<<dim3(NDESC), 256, 0, stream>>>(hT, m_non, m_uni, counts, bucket, desc,
                                                  WpG, bih, bhh);
    }
}

// Round 12
// 832.336 us; speedup vs baseline: 1.0580x; 1.0281x over previous
//
#include <hip/hip_runtime.h>
#include <math.h>

#define NBOND 7
#define NLAY 8
#define NTYPE 6
#define NNODES 16384   // B*N = 128*128
#define PX 136         // LDS pitch in halves for X rows (272 B)
#define PXT 68         // LDS pitch in halves for Xt rows (136 B; 8B-aligned, 2-way-free)
#define NDESC 520      // 8 XCDs x 65 desc slots (>= 518 max active 32-node slices)

typedef _Float16 half8 __attribute__((ext_vector_type(8)));
typedef _Float16 half4 __attribute__((ext_vector_type(4)));
typedef float floatx16 __attribute__((ext_vector_type(16)));

__device__ __forceinline__ float sig_(float x) { return 1.0f / (1.0f + __expf(-x)); }
// D-layout for 32x32 MFMA: col = lane&31, row = (reg&3) + 8*(reg>>2) + 4*(lane>>5)
__device__ __forceinline__ int drow_(int reg, int hi) { return (reg & 3) + 8 * (reg >> 2) + 4 * hi; }

__device__ __forceinline__ _Float16 hi_(float v) { return (_Float16)v; }
__device__ __forceinline__ _Float16 lo_(float v) { return (_Float16)(v - (float)(_Float16)v); }

// 8B-aligned half8 load as two half4 (Xt pitch 68 halves is 8-mod-16 for odd rows)
__device__ __forceinline__ half8 ld_h8_2x64(const _Float16* p) {
    half4 a = *(const half4*)p;
    half4 b = *(const half4*)(p + 4);
    half8 r = {a[0], a[1], a[2], a[3], b[0], b[1], b[2], b[3]};
    return r;
}

// ---------------------------------------------------------------- setup
__global__ void setup_kernel(const float* __restrict__ h, float* __restrict__ hT,
                             int* __restrict__ counts, int* __restrict__ bucket)
{
    int gid = blockIdx.x * 256 + threadIdx.x;
    int node = gid >> 7, d = gid & 127;
    hT[gid] = (d < 75) ? h[node * 75 + d] : 0.0f;
    if (gid < NNODES) {
        float a = h[gid * 75];
        int tt = 5;
        if      (a == 6.0f) tt = 0;
        else if (a == 7.0f) tt = 1;
        else if (a == 8.0f) tt = 2;
        else if (a == 9.0f) tt = 3;
        else if (a == 0.0f) tt = 4;
        int slot = atomicAdd(&counts[tt], 1);
        bucket[tt * NNODES + slot] = gid;
    }
}

// Dense GRU block descriptors over 32-node slices (r8 form): desc[i] = tt | (slice<<3).
__global__ void build_desc_kernel(const int* __restrict__ counts, int* __restrict__ desc)
{
    if (threadIdx.x != 0 || blockIdx.x != 0) return;
    int i = 0;
    for (int tt = 0; tt < NTYPE; ++tt) {
        int nb = (counts[tt] + 31) >> 5;
        for (int s = 0; s < nb; ++s) desc[i++] = tt | (s << 3);
    }
    while (i < NDESC) desc[i++] = -1;
}

// ---------------------------------------------------------------- weight packing (fp32 -> split fp16 hi/lo planes)
// msgW: [(kb*8+l)][c 0..15][plane hi/lo][e 0..127][j 0..7]  (j along input dim d)
__global__ void pack_msg_kernel(const float* __restrict__ msgW, _Float16* __restrict__ Wp)
{
    int idx = blockIdx.x * 256 + threadIdx.x;
    if (idx >= NBOND * NLAY * 16 * 128) return;
    int e  = idx & 127;
    int c  = (idx >> 7) & 15;
    int kl = idx >> 11;
    const float* src = msgW + ((size_t)kl * 128 + e) * 128 + c * 8;
    float4 u = *(const float4*)src;
    float4 v = *(const float4*)(src + 4);
    float av[8] = {u.x, u.y, u.z, u.w, v.x, v.y, v.z, v.w};
    half8 hh, ll;
    #pragma unroll
    for (int j = 0; j < 8; ++j) { hh[j] = hi_(av[j]); ll[j] = lo_(av[j]); }
    _Float16* dst = Wp + ((size_t)kl * 16 + c) * 2048;
    *(half8*)(dst + e * 8)        = hh;
    *(half8*)(dst + 1024 + e * 8) = ll;
}

// GRU: [(vt*2+mat)][c 0..15][plane hi/lo][col 0..383][j 0..7]
__global__ void pack_gru_kernel(const float* __restrict__ Wih, const float* __restrict__ Whh,
                                _Float16* __restrict__ Wp)
{
    int idx = blockIdx.x * 256 + threadIdx.x;
    if (idx >= 2 * NTYPE * 2 * 16 * 384) return;
    int col = idx % 384;
    int c   = (idx / 384) & 15;
    int vm  = idx / 6144;       // (vt*2 + mat), vt = v*6+tt
    int mat = vm & 1;
    int vt  = vm >> 1;
    const float* src = (mat ? Whh : Wih) + ((size_t)vt * 384 + col) * 128 + c * 8;
    float4 u = *(const float4*)src;
    float4 v = *(const float4*)(src + 4);
    float av[8] = {u.x, u.y, u.z, u.w, v.x, v.y, v.z, v.w};
    half8 hh, ll;
    #pragma unroll
    for (int j = 0; j < 8; ++j) { hh[j] = hi_(av[j]); ll[j] = lo_(av[j]); }
    _Float16* dst = Wp + (size_t)vm * 98304 + (size_t)c * 6144;
    *(half8*)(dst + col * 8)        = hh;
    *(half8*)(dst + 3072 + col * 8) = ll;
}

// ---------------------------------------------------------------- MLP + aggregation (split-fp16 MFMA)
// HALF-MOLECULE blocks: one block per (kb, nb) where nb indexes 64-node halves
// (molecule b = nb>>1). 256 threads / 4 waves, LDS 34.8 KB -> 4 INDEPENDENT
// blocks/CU (4 waves/SIMD from 4 different blocks at uncorrelated barrier
// phases — r4's 2 coupled 8-wave blocks stalled together; this decorrelates).
// MLP: wave w = col-tile w, both 32-row tiles: per kk 2 W loads -> 6 MFMAs.
// Agg: K=64 (own half's xb): partial sums atomicAdd'ed into m_non/m_uni.
// Grid dim3(256,7): consecutive bids share kb -> L1/L2 weight reuse.
__global__ __launch_bounds__(256, 4) void mlp_agg_mfma(
    const float* __restrict__ hin, const _Float16* __restrict__ Wp,
    const float* __restrict__ gmat, float* __restrict__ m_non, float* __restrict__ m_uni)
{
    __shared__ _Float16 Xhi[64 * PX];   // 8704 halves; reused as Xt[128][PXT] (8704)
    __shared__ _Float16 Xlo[64 * PX];

    const int nb = blockIdx.x, kb = blockIdx.y;
    const int b = nb >> 1, mh = nb & 1;          // molecule, m-half
    const int t = threadIdx.x;
    const int wave = t >> 6, lane = t & 63, lo = lane & 31, hi = lane >> 5;
    const int wcol = wave * 32 + lo;             // MLP-phase output column (4 waves = 128 cols)

    // stage layer-0 activations for this 64-node half (fp32 -> hi/lo fp16)
    for (int q = t; q < 64 * 32; q += 256) {
        int r = q >> 5, c4 = q & 31;
        float4 v = *(const float4*)(hin + ((size_t)(nb * 64 + r)) * 128 + c4 * 4);
        half4 hh, ll;
        hh[0] = hi_(v.x); ll[0] = lo_(v.x);
        hh[1] = hi_(v.y); ll[1] = lo_(v.y);
        hh[2] = hi_(v.z); ll[2] = lo_(v.z);
        hh[3] = hi_(v.w); ll[3] = lo_(v.w);
        *(half4*)(Xhi + r * PX + c4 * 4) = hh;
        *(half4*)(Xlo + r * PX + c4 * 4) = ll;
    }
    __syncthreads();

    floatx16 acc[2];

    #pragma unroll 1
    for (int l = 0; l < NLAY; ++l) {
        #pragma unroll
        for (int r2 = 0; r2 < 2; ++r2) acc[r2] = (floatx16)0.0f;
        const _Float16* wb = Wp + ((size_t)(kb * NLAY + l) * 16) * 2048;

        #pragma unroll
        for (int kk = 0; kk < 8; ++kk) {
            const _Float16* bp = wb + (size_t)(kk * 2 + hi) * 2048;
            half8 b_h = *(const half8*)(bp + wcol * 8);
            half8 b_l = *(const half8*)(bp + 1024 + wcol * 8);
            #pragma unroll
            for (int r2 = 0; r2 < 2; ++r2) {
                int rrow = r2 * 32 + lo;
                half8 a_h = *(const half8*)(Xhi + rrow * PX + kk * 16 + hi * 8);
                half8 a_l = *(const half8*)(Xlo + rrow * PX + kk * 16 + hi * 8);
                acc[r2] = __builtin_amdgcn_mfma_f32_32x32x16_f16(a_h, b_h, acc[r2], 0, 0, 0);
                acc[r2] = __builtin_amdgcn_mfma_f32_32x32x16_f16(a_h, b_l, acc[r2], 0, 0, 0);
                acc[r2] = __builtin_amdgcn_mfma_f32_32x32x16_f16(a_l, b_h, acc[r2], 0, 0, 0);
            }
        }
        __syncthreads();   // all waves' X reads for layer l done

        if (l < NLAY - 1) {
            // writeback: fixed column wcol, rows r2*32+drow
            #pragma unroll
            for (int r2 = 0; r2 < 2; ++r2)
                #pragma unroll
                for (int reg = 0; reg < 16; ++reg) {
                    int n = r2 * 32 + drow_(reg, hi);
                    float vv = fmaxf(acc[r2][reg], 0.0f);
                    Xhi[n * PX + wcol] = hi_(vv);
                    Xlo[n * PX + wcol] = lo_(vv);
                }
        } else {
            // final layer: Xt[e][m] (e = wcol, pitch PXT=68, m in 0..63): contiguous half4 in m
            #pragma unroll
            for (int r2 = 0; r2 < 2; ++r2)
                #pragma unroll
                for (int s = 0; s < 4; ++s) {
                    int m0 = r2 * 32 + 8 * s + 4 * hi;
                    half4 hh, ll;
                    #pragma unroll
                    for (int j = 0; j < 4; ++j) {
                        float vv = acc[r2][4 * s + j];
                        hh[j] = hi_(vv); ll[j] = lo_(vv);
                    }
                    *(half4*)(Xhi + wcol * PXT + m0) = hh;
                    *(half4*)(Xlo + wcol * PXT + m0) = ll;
                }
        }
        __syncthreads();
    }

    // ---- aggregation (partial over this half's 64 m's):
    // m[n][d] += sum_{m in half} g[b,kb,n,m] * xb[m][d]; all 128 n, K=64.
    // wave w = n-tile w (rows w*32..+31), all 4 d-tiles.
    floatx16 agg[4];
    #pragma unroll
    for (int ct = 0; ct < 4; ++ct) agg[ct] = (floatx16)0.0f;
    const float* grow = gmat + (size_t)(b * NBOND + kb) * 16384;
    const int row = wave * 32 + lo;   // n

    #pragma unroll
    for (int kk = 0; kk < 4; ++kk) {
        const float* gp = grow + (size_t)row * 128 + mh * 64 + kk * 16 + hi * 8;
        float4 u = *(const float4*)gp, v2 = *(const float4*)(gp + 4);
        float av[8] = {u.x, u.y, u.z, u.w, v2.x, v2.y, v2.z, v2.w};
        half8 a_h, a_l;
        #pragma unroll
        for (int j = 0; j < 8; ++j) { a_h[j] = hi_(av[j]); a_l[j] = lo_(av[j]); }
        #pragma unroll
        for (int ct = 0; ct < 4; ++ct) {
            half8 b_h = ld_h8_2x64(Xhi + (ct * 32 + lo) * PXT + kk * 16 + hi * 8);
            half8 b_l = ld_h8_2x64(Xlo + (ct * 32 + lo) * PXT + kk * 16 + hi * 8);
            agg[ct] = __builtin_amdgcn_mfma_f32_32x32x16_f16(a_h, b_h, agg[ct], 0, 0, 0);
            agg[ct] = __builtin_amdgcn_mfma_f32_32x32x16_f16(a_h, b_l, agg[ct], 0, 0, 0);
            agg[ct] = __builtin_amdgcn_mfma_f32_32x32x16_f16(a_l, b_h, agg[ct], 0, 0, 0);
        }
    }

    float* mdst = (kb == NBOND - 1) ? m_uni : m_non;
    #pragma unroll
    for (int ct = 0; ct < 4; ++ct)
        #pragma unroll
        for (int reg = 0; reg < 16; ++reg) {
            int n = wave * 32 + drow_(reg, hi);
            atomicAdd(mdst + ((size_t)(b * 128 + n)) * 128 + ct * 32 + lo, agg[ct][reg]);
        }
}

// ---------------------------------------------------------------- grouped GRU (split-fp16 MFMA) — r8 exact (best measured)
// Dense grid of NDESC blocks; block -> (tt, slice) via desc with XCD-chunked
// mapping. One block = 32 gathered nodes of one type, BOTH GRU variants
// (v-loop, M restaged per v). LDS 35 KB -> 4 blocks/CU. Block owns its nodes
// exclusively -> in-place hT update: v=0 stores, v=1 read-add-stores.
__global__ __launch_bounds__(256, 3) void gru_mfma(
    float* __restrict__ hT,
    const float* __restrict__ m_non, const float* __restrict__ m_uni,
    const int* __restrict__ counts, const int* __restrict__ bucket,
    const int* __restrict__ desc,
    const _Float16* __restrict__ Wp, const float* __restrict__ bihp, const float* __restrict__ bhhp)
{
    __shared__ _Float16 Xh[32 * PX], Xl[32 * PX], Mh[32 * PX], Ml[32 * PX];
    __shared__ int bl[32];

    const int bid = blockIdx.x;
    const int dv = desc[(bid & 7) * (NDESC / 8) + (bid >> 3)];
    if (dv < 0) return;
    const int tt = dv & 7;
    const int base = (dv >> 3) * 32;
    const int t = threadIdx.x;
    const int cnt = counts[tt];
    const int nn = min(32, cnt - base);
    if (t < 32) bl[t] = (t < nn) ? bucket[tt * NNODES + base + t] : -1;
    __syncthreads();

    // stage X once (gathered h rows, split fp16, zero-fill inactive)
    for (int q = t; q < 32 * 32; q += 256) {
        int r = q >> 5, c4 = q & 31;
        float4 xv = make_float4(0.f, 0.f, 0.f, 0.f);
        int node = bl[r];
        if (node >= 0) xv = *(const float4*)(hT + (size_t)node * 128 + c4 * 4);
        half4 hh, ll;
        hh[0] = hi_(xv.x); ll[0] = lo_(xv.x);
        hh[1] = hi_(xv.y); ll[1] = lo_(xv.y);
        hh[2] = hi_(xv.z); ll[2] = lo_(xv.z);
        hh[3] = hi_(xv.w); ll[3] = lo_(xv.w);
        *(half4*)(Xh + r * PX + c4 * 4) = hh;
        *(half4*)(Xl + r * PX + c4 * 4) = ll;
    }

    const int wave = t >> 6, lane = t & 63, lo = lane & 31, hi = lane >> 5;
    const int d = wave * 32 + lo;

    #pragma unroll 1
    for (int v = 0; v < 2; ++v) {
        const float* msrc = v ? m_uni : m_non;
        __syncthreads();   // v=0: X-stage commit; v=1: prior M readers done
        for (int q = t; q < 32 * 32; q += 256) {
            int r = q >> 5, c4 = q & 31;
            float4 mv = make_float4(0.f, 0.f, 0.f, 0.f);
            int node = bl[r];
            if (node >= 0) mv = *(const float4*)(msrc + (size_t)node * 128 + c4 * 4);
            half4 hh, ll;
            hh[0] = hi_(mv.x); ll[0] = lo_(mv.x);
            hh[1] = hi_(mv.y); ll[1] = lo_(mv.y);
            hh[2] = hi_(mv.z); ll[2] = lo_(mv.z);
            hh[3] = hi_(mv.w); ll[3] = lo_(mv.w);
            *(half4*)(Mh + r * PX + c4 * 4) = hh;
            *(half4*)(Ml + r * PX + c4 * 4) = ll;
        }
        __syncthreads();

        const int vt = v * NTYPE + tt;
        const _Float16* pih = Wp + (size_t)(vt * 2 + 0) * 98304;
        const _Float16* phh = Wp + (size_t)(vt * 2 + 1) * 98304;

        floatx16 ar = (floatx16)0.0f, az = (floatx16)0.0f;
        floatx16 ax = (floatx16)0.0f, ah = (floatx16)0.0f;

        #pragma unroll 2
        for (int kk = 0; kk < 8; ++kk) {
            int koff = kk * 16 + hi * 8;
            half8 xh = *(const half8*)(Xh + lo * PX + koff);
            half8 xl = *(const half8*)(Xl + lo * PX + koff);
            half8 mh = *(const half8*)(Mh + lo * PX + koff);
            half8 ml = *(const half8*)(Ml + lo * PX + koff);
            const _Float16* ci = pih + (size_t)(kk * 2 + hi) * 6144;
            const _Float16* ch = phh + (size_t)(kk * 2 + hi) * 6144;
            half8 birh = *(const half8*)(ci + (0   + d) * 8);
            half8 birl = *(const half8*)(ci + 3072 + (0   + d) * 8);
            half8 bizh = *(const half8*)(ci + (128 + d) * 8);
            half8 bizl = *(const half8*)(ci + 3072 + (128 + d) * 8);
            half8 binh = *(const half8*)(ci + (256 + d) * 8);
            half8 binl = *(const half8*)(ci + 3072 + (256 + d) * 8);
            half8 bhrh = *(const half8*)(ch + (0   + d) * 8);
            half8 bhrl = *(const half8*)(ch + 3072 + (0   + d) * 8);
            half8 bhzh = *(const half8*)(ch + (128 + d) * 8);
            half8 bhzl = *(const half8*)(ch + 3072 + (128 + d) * 8);
            half8 bhnh = *(const half8*)(ch + (256 + d) * 8);
            half8 bhnl = *(const half8*)(ch + 3072 + (256 + d) * 8);

            ar = __builtin_amdgcn_mfma_f32_32x32x16_f16(xh, birh, ar, 0, 0, 0);
            ar = __builtin_amdgcn_mfma_f32_32x32x16_f16(xh, birl, ar, 0, 0, 0);
            ar = __builtin_amdgcn_mfma_f32_32x32x16_f16(xl, birh, ar, 0, 0, 0);
            ar = __builtin_amdgcn_mfma_f32_32x32x16_f16(mh, bhrh, ar, 0, 0, 0);
            ar = __builtin_amdgcn_mfma_f32_32x32x16_f16(mh, bhrl, ar, 0, 0, 0);
            ar = __builtin_amdgcn_mfma_f32_32x32x16_f16(ml, bhrh, ar, 0, 0, 0);

            az = __builtin_amdgcn_mfma_f32_32x32x16_f16(xh, bizh, az, 0, 0, 0);
            az = __builtin_amdgcn_mfma_f32_32x32x16_f16(xh, bizl, az, 0, 0, 0);
            az = __builtin_amdgcn_mfma_f32_32x32x16_f16(xl, bizh, az, 0, 0, 0);
            az = __builtin_amdgcn_mfma_f32_32x32x16_f16(mh, bhzh, az, 0, 0, 0);
            az = __builtin_amdgcn_mfma_f32_32x32x16_f16(mh, bhzl, az, 0, 0, 0);
            az = __builtin_amdgcn_mfma_f32_32x32x16_f16(ml, bhzh, az, 0, 0, 0);

            ax = __builtin_amdgcn_mfma_f32_32x32x16_f16(xh, binh, ax, 0, 0, 0);
            ax = __builtin_amdgcn_mfma_f32_32x32x16_f16(xh, binl, ax, 0, 0, 0);
            ax = __builtin_amdgcn_mfma_f32_32x32x16_f16(xl, binh, ax, 0, 0, 0);
            ah = __builtin_amdgcn_mfma_f32_32x32x16_f16(mh, bhnh, ah, 0, 0, 0);
            ah = __builtin_amdgcn_mfma_f32_32x32x16_f16(mh, bhnl, ah, 0, 0, 0);
            ah = __builtin_amdgcn_mfma_f32_32x32x16_f16(ml, bhnh, ah, 0, 0, 0);
        }

        const float* bi = bihp + (size_t)vt * 384;
        const float* bh = bhhp + (size_t)vt * 384;
        float b_r  = bi[d] + bh[d];
        float b_z  = bi[128 + d] + bh[128 + d];
        float b_in = bi[256 + d];
        float b_hn = bh[256 + d];
        #pragma unroll
        for (int reg = 0; reg < 16; ++reg) {
            int n = drow_(reg, hi);
            int node = bl[n];
            if (node < 0) continue;
            float r  = sig_(ar[reg] + b_r);
            float z  = sig_(az[reg] + b_z);
            float nv = tanhf(ax[reg] + b_in + r * (ah[reg] + b_hn));
            float mv = msrc[(size_t)node * 128 + d];   // fp32 m for z*m
            float val = (1.0f - z) * nv + z * mv;
            if (v == 0) hT[(size_t)node * 128 + d] = val;                       // overwrite old h
            else        hT[(size_t)node * 128 + d] += val;                      // block owns node
        }
    }
}

// ---------------------------------------------------------------- launch
extern "C" void kernel_launch(void* const* d_in, const int* in_sizes, int n_in,
                              void* d_out, int out_size, void* d_ws, size_t ws_size,
                              hipStream_t stream) {
    const float* g    = (const float*)d_in[0];
    const float* h    = (const float*)d_in[1];
    const float* msgW = (const float*)d_in[2];
    const float* Wih  = (const float*)d_in[3];
    const float* Whh  = (const float*)d_in[4];
    const float* bih  = (const float*)d_in[5];
    const float* bhh  = (const float*)d_in[6];
    float* hT = (float*)d_out;

    char* ws = (char*)d_ws;
    float* m_non = (float*)ws;                                   // 8 MB
    float* m_uni = m_non + (size_t)NNODES * 128;                 // 8 MB (contiguous with m_non)
    int* counts  = (int*)(ws + 2 * (size_t)NNODES * 128 * 4);
    int* bucket  = counts + 8;                                   // [6][16384]
    int* desc    = bucket + NTYPE * NNODES;                      // [520]
    _Float16* WpM = (_Float16*)(desc + NDESC);                   // 1,835,008 halves (3.67 MB)
    _Float16* WpG = WpM + (size_t)NBOND * NLAY * 16 * 2048;      // 2,359,296 halves (4.72 MB)

    (void)hipMemsetAsync(counts, 0, 8 * sizeof(int), stream);
    setup_kernel<<<NNODES * 128 / 256, 256, 0, stream>>>(h, hT, counts, bucket);
    build_desc_kernel<<<1, 64, 0, stream>>>(counts, desc);
    pack_msg_kernel<<<(NBOND * NLAY * 16 * 128 + 255) / 256, 256, 0, stream>>>(msgW, WpM);
    pack_gru_kernel<<<(2 * NTYPE * 2 * 16 * 384 + 255) / 256, 256, 0, stream>>>(Wih, Whh, WpG);

    for (int pass = 0; pass < 3; ++pass) {
        // both m_non and m_uni are atomic partial-sum targets now (contiguous: one memset)
        (void)hipMemsetAsync(m_non, 0, 2 * (size_t)NNODES * 128 * 4, stream);
        mlp_agg_mfma<<<dim3(256, NBOND), 256, 0, stream>>>(hT, WpM, g, m_non, m_uni);
        gru_mfma<<<dim3(NDESC), 256, 0, stream>>>(hT, m_non, m_uni, counts, bucket, desc,
                                                  WpG, bih, bhh);
    }
}

// Round 13
// 814.988 us; speedup vs baseline: 1.0806x; 1.0213x over previous
//
#include <hip/hip_runtime.h>
#include <math.h>

#define NBOND 7
#define NLAY 8
#define NTYPE 6
#define NNODES 16384   // B*N = 128*128
#define PX 136         // LDS pitch in halves (272 B, 16B-aligned; 68 dw % 32 = 4 -> conflict-clean)
#define NDESC 264      // 8 XCDs x 33 desc slots (>= 262 max active 64-node slices)

typedef _Float16 half8 __attribute__((ext_vector_type(8)));
typedef _Float16 half4 __attribute__((ext_vector_type(4)));
typedef float floatx16 __attribute__((ext_vector_type(16)));

__device__ __forceinline__ float sig_(float x) { return 1.0f / (1.0f + __expf(-x)); }
// D-layout for 32x32 MFMA: col = lane&31, row = (reg&3) + 8*(reg>>2) + 4*(lane>>5)
__device__ __forceinline__ int drow_(int reg, int hi) { return (reg & 3) + 8 * (reg >> 2) + 4 * hi; }

__device__ __forceinline__ _Float16 hi_(float v) { return (_Float16)v; }
__device__ __forceinline__ _Float16 lo_(float v) { return (_Float16)(v - (float)(_Float16)v); }

// ---------------------------------------------------------------- setup
__global__ void setup_kernel(const float* __restrict__ h, float* __restrict__ hT,
                             int* __restrict__ counts, int* __restrict__ bucket)
{
    int gid = blockIdx.x * 256 + threadIdx.x;
    int node = gid >> 7, d = gid & 127;
    hT[gid] = (d < 75) ? h[node * 75 + d] : 0.0f;
    if (gid < NNODES) {
        float a = h[gid * 75];
        int tt = 5;
        if      (a == 6.0f) tt = 0;
        else if (a == 7.0f) tt = 1;
        else if (a == 8.0f) tt = 2;
        else if (a == 9.0f) tt = 3;
        else if (a == 0.0f) tt = 4;
        int slot = atomicAdd(&counts[tt], 1);
        bucket[tt * NNODES + slot] = gid;
    }
}

// Dense GRU block descriptors over 64-node slices: desc[i] = tt | (slice<<3).
__global__ void build_desc_kernel(const int* __restrict__ counts, int* __restrict__ desc)
{
    if (threadIdx.x != 0 || blockIdx.x != 0) return;
    int i = 0;
    for (int tt = 0; tt < NTYPE; ++tt) {
        int nb = (counts[tt] + 63) >> 6;
        for (int s = 0; s < nb; ++s) desc[i++] = tt | (s << 3);
    }
    while (i < NDESC) desc[i++] = -1;
}

// ---------------------------------------------------------------- weight packing (fp32 -> split fp16 hi/lo planes)
// msgW: [(kb*8+l)][c 0..15][plane hi/lo][e 0..127][j 0..7]  (j along input dim d)
__global__ void pack_msg_kernel(const float* __restrict__ msgW, _Float16* __restrict__ Wp)
{
    int idx = blockIdx.x * 256 + threadIdx.x;
    if (idx >= NBOND * NLAY * 16 * 128) return;
    int e  = idx & 127;
    int c  = (idx >> 7) & 15;
    int kl = idx >> 11;
    const float* src = msgW + ((size_t)kl * 128 + e) * 128 + c * 8;
    float4 u = *(const float4*)src;
    float4 v = *(const float4*)(src + 4);
    float av[8] = {u.x, u.y, u.z, u.w, v.x, v.y, v.z, v.w};
    half8 hh, ll;
    #pragma unroll
    for (int j = 0; j < 8; ++j) { hh[j] = hi_(av[j]); ll[j] = lo_(av[j]); }
    _Float16* dst = Wp + ((size_t)kl * 16 + c) * 2048;
    *(half8*)(dst + e * 8)        = hh;
    *(half8*)(dst + 1024 + e * 8) = ll;
}

// GRU: [(vt*2+mat)][c 0..15][plane hi/lo][col 0..383][j 0..7]
__global__ void pack_gru_kernel(const float* __restrict__ Wih, const float* __restrict__ Whh,
                                _Float16* __restrict__ Wp)
{
    int idx = blockIdx.x * 256 + threadIdx.x;
    if (idx >= 2 * NTYPE * 2 * 16 * 384) return;
    int col = idx % 384;
    int c   = (idx / 384) & 15;
    int vm  = idx / 6144;       // (vt*2 + mat), vt = v*6+tt
    int mat = vm & 1;
    int vt  = vm >> 1;
    const float* src = (mat ? Whh : Wih) + ((size_t)vt * 384 + col) * 128 + c * 8;
    float4 u = *(const float4*)src;
    float4 v = *(const float4*)(src + 4);
    float av[8] = {u.x, u.y, u.z, u.w, v.x, v.y, v.z, v.w};
    half8 hh, ll;
    #pragma unroll
    for (int j = 0; j < 8; ++j) { hh[j] = hi_(av[j]); ll[j] = lo_(av[j]); }
    _Float16* dst = Wp + (size_t)vm * 98304 + (size_t)c * 6144;
    *(half8*)(dst + col * 8)        = hh;
    *(half8*)(dst + 3072 + col * 8) = ll;
}

// ---------------------------------------------------------------- MLP + aggregation (split-fp16 MFMA)
// r8-exact (best measured: 150.5 us): one block per (kb, b), 512 threads /
// 8 waves over the 68 KB tile -> 2 blocks/CU, 4 waves/SIMD.
// MLP: wave w = (col-tile w&3) x (row-half w>>2): per kk 2 weight loads (L2)
// feed 6 MFMAs. Agg: wave w = (row-tile w&3) x (col-half w>>2).
__global__ __launch_bounds__(512, 4) void mlp_agg_mfma(
    const float* __restrict__ hin, const _Float16* __restrict__ Wp,
    const float* __restrict__ gmat, float* __restrict__ m_non, float* __restrict__ m_uni)
{
    __shared__ _Float16 Xhi[128 * PX];
    __shared__ _Float16 Xlo[128 * PX];

    const int t = threadIdx.x;
    const int kb = blockIdx.x, b = blockIdx.y;
    const int wave = t >> 6, lane = t & 63, lo = lane & 31, hi = lane >> 5;
    const int ctw = wave & 3, rh = wave >> 2;   // MLP: col-tile, row-half
    const int wcol = ctw * 32 + lo;             // MLP-phase output column

    // stage layer-0 activations (fp32 -> hi/lo fp16)
    for (int q = t; q < 128 * 32; q += 512) {
        int r = q >> 5, c4 = q & 31;
        float4 v = *(const float4*)(hin + ((size_t)(b * 128 + r)) * 128 + c4 * 4);
        half4 hh, ll;
        hh[0] = hi_(v.x); ll[0] = lo_(v.x);
        hh[1] = hi_(v.y); ll[1] = lo_(v.y);
        hh[2] = hi_(v.z); ll[2] = lo_(v.z);
        hh[3] = hi_(v.w); ll[3] = lo_(v.w);
        *(half4*)(Xhi + r * PX + c4 * 4) = hh;
        *(half4*)(Xlo + r * PX + c4 * 4) = ll;
    }
    __syncthreads();

    floatx16 acc[2];

    #pragma unroll 1
    for (int l = 0; l < NLAY; ++l) {
        #pragma unroll
        for (int r2 = 0; r2 < 2; ++r2) acc[r2] = (floatx16)0.0f;
        const _Float16* wb = Wp + ((size_t)(kb * NLAY + l) * 16) * 2048;

        #pragma unroll
        for (int kk = 0; kk < 8; ++kk) {
            const _Float16* bp = wb + (size_t)(kk * 2 + hi) * 2048;
            half8 b_h = *(const half8*)(bp + wcol * 8);
            half8 b_l = *(const half8*)(bp + 1024 + wcol * 8);
            #pragma unroll
            for (int r2 = 0; r2 < 2; ++r2) {
                int rrow = (rh * 2 + r2) * 32 + lo;
                half8 a_h = *(const half8*)(Xhi + rrow * PX + kk * 16 + hi * 8);
                half8 a_l = *(const half8*)(Xlo + rrow * PX + kk * 16 + hi * 8);
                acc[r2] = __builtin_amdgcn_mfma_f32_32x32x16_f16(a_h, b_h, acc[r2], 0, 0, 0);
                acc[r2] = __builtin_amdgcn_mfma_f32_32x32x16_f16(a_h, b_l, acc[r2], 0, 0, 0);
                acc[r2] = __builtin_amdgcn_mfma_f32_32x32x16_f16(a_l, b_h, acc[r2], 0, 0, 0);
            }
        }
        __syncthreads();   // all waves' X reads for layer l done

        if (l < NLAY - 1) {
            // writeback: fixed column wcol, rows (rh*2+r2)*32+drow
            #pragma unroll
            for (int r2 = 0; r2 < 2; ++r2)
                #pragma unroll
                for (int reg = 0; reg < 16; ++reg) {
                    int n = (rh * 2 + r2) * 32 + drow_(reg, hi);
                    float vv = fmaxf(acc[r2][reg], 0.0f);
                    Xhi[n * PX + wcol] = hi_(vv);
                    Xlo[n * PX + wcol] = lo_(vv);
                }
        } else {
            // final layer: Xt[e][m]; lane's fixed dim IS e=wcol -> contiguous half4 in m
            #pragma unroll
            for (int r2 = 0; r2 < 2; ++r2)
                #pragma unroll
                for (int s = 0; s < 4; ++s) {
                    int m0 = (rh * 2 + r2) * 32 + 8 * s + 4 * hi;
                    half4 hh, ll;
                    #pragma unroll
                    for (int j = 0; j < 4; ++j) {
                        float vv = acc[r2][4 * s + j];
                        hh[j] = hi_(vv); ll[j] = lo_(vv);
                    }
                    *(half4*)(Xhi + wcol * PX + m0) = hh;
                    *(half4*)(Xlo + wcol * PX + m0) = ll;
                }
        }
        __syncthreads();
    }

    // ---- aggregation: m[n][d] = sum_m g[b,kb,n,m]*xb[m][d]; A = g (inline split), B = Xt ----
    const int rtw = wave & 3, ch = wave >> 2;
    const int row = rtw * 32 + lo;
    #pragma unroll
    for (int c2 = 0; c2 < 2; ++c2) acc[c2] = (floatx16)0.0f;
    const float* grow = gmat + (size_t)(b * NBOND + kb) * 16384;

    #pragma unroll 2
    for (int kk = 0; kk < 8; ++kk) {
        const float* gp = grow + (size_t)row * 128 + kk * 16 + hi * 8;
        float4 u = *(const float4*)gp, v2 = *(const float4*)(gp + 4);
        float av[8] = {u.x, u.y, u.z, u.w, v2.x, v2.y, v2.z, v2.w};
        half8 a_h, a_l;
        #pragma unroll
        for (int j = 0; j < 8; ++j) { a_h[j] = hi_(av[j]); a_l[j] = lo_(av[j]); }
        #pragma unroll
        for (int c2 = 0; c2 < 2; ++c2) {
            int ct = ch * 2 + c2;
            half8 b_h = *(const half8*)(Xhi + (ct * 32 + lo) * PX + kk * 16 + hi * 8);
            half8 b_l = *(const half8*)(Xlo + (ct * 32 + lo) * PX + kk * 16 + hi * 8);
            acc[c2] = __builtin_amdgcn_mfma_f32_32x32x16_f16(a_h, b_h, acc[c2], 0, 0, 0);
            acc[c2] = __builtin_amdgcn_mfma_f32_32x32x16_f16(a_h, b_l, acc[c2], 0, 0, 0);
            acc[c2] = __builtin_amdgcn_mfma_f32_32x32x16_f16(a_l, b_h, acc[c2], 0, 0, 0);
        }
    }

    if (kb == NBOND - 1) {
        #pragma unroll
        for (int c2 = 0; c2 < 2; ++c2)
            #pragma unroll
            for (int reg = 0; reg < 16; ++reg) {
                int n = rtw * 32 + drow_(reg, hi);
                m_uni[((size_t)(b * 128 + n)) * 128 + (ch * 2 + c2) * 32 + lo] = acc[c2][reg];
            }
    } else {
        #pragma unroll
        for (int c2 = 0; c2 < 2; ++c2)
            #pragma unroll
            for (int reg = 0; reg < 16; ++reg) {
                int n = rtw * 32 + drow_(reg, hi);
                atomicAdd(m_non + ((size_t)(b * 128 + n)) * 128 + (ch * 2 + c2) * 32 + lo,
                          acc[c2][reg]);
            }
    }
}

// ---------------------------------------------------------------- grouped GRU (split-fp16 MFMA)
// 64-node slices x d-half grid: block = (desc slice, dh = blockIdx.y).
// ~516 active blocks -> 2 blocks/CU (LDS 69.6 KB) = r8's TLP, while weight
// traffic HALVES vs r8 (each block reads only its 64 d-columns: 393 KB/block,
// ~203 MB total vs 398 MB). Both v's accumulate in registers (hacc) -> ONE
// plain store per output element in the block's exclusive d-columns: no
// atomics, no output memset (vs r10's regression). h ping-pongs ws<->d_out.
// 4 waves = (r2-half = wave>>1) x (d-tile = wave&1); per-wave inner structure
// identical to r8 (18 MFMAs : 12 weight loads per kk, 4 acc chains).
__global__ __launch_bounds__(256, 2) void gru_mfma(
    const float* __restrict__ hin, float* __restrict__ hout,
    const float* __restrict__ m_non, const float* __restrict__ m_uni,
    const int* __restrict__ counts, const int* __restrict__ bucket,
    const int* __restrict__ desc,
    const _Float16* __restrict__ Wp, const float* __restrict__ bihp, const float* __restrict__ bhhp)
{
    __shared__ _Float16 Xh[64 * PX], Xl[64 * PX], Mh[64 * PX], Ml[64 * PX];
    __shared__ int bl[64];

    const int bid = blockIdx.x;
    const int dv = desc[(bid & 7) * (NDESC / 8) + (bid >> 3)];
    if (dv < 0) return;
    const int tt = dv & 7;
    const int dh = blockIdx.y;               // d-half this block owns
    const int base = (dv >> 3) * 64;
    const int t = threadIdx.x;
    const int cnt = counts[tt];
    const int nn = min(64, cnt - base);
    if (t < 64) bl[t] = (t < nn) ? bucket[tt * NNODES + base + t] : -1;
    __syncthreads();

    // stage X once (64 gathered h rows, FULL 128-d K range, split fp16)
    for (int q = t; q < 64 * 32; q += 256) {
        int r = q >> 5, c4 = q & 31;
        float4 xv = make_float4(0.f, 0.f, 0.f, 0.f);
        int node = bl[r];
        if (node >= 0) xv = *(const float4*)(hin + (size_t)node * 128 + c4 * 4);
        half4 hh, ll;
        hh[0] = hi_(xv.x); ll[0] = lo_(xv.x);
        hh[1] = hi_(xv.y); ll[1] = lo_(xv.y);
        hh[2] = hi_(xv.z); ll[2] = lo_(xv.z);
        hh[3] = hi_(xv.w); ll[3] = lo_(xv.w);
        *(half4*)(Xh + r * PX + c4 * 4) = hh;
        *(half4*)(Xl + r * PX + c4 * 4) = ll;
    }

    const int wave = t >> 6, lane = t & 63, lo = lane & 31, hi = lane >> 5;
    const int r2 = wave >> 1;                // node half (rows r2*32..+31)
    const int d = dh * 64 + (wave & 1) * 32 + lo;   // output dim this lane owns

    float hacc[16];
    #pragma unroll
    for (int reg = 0; reg < 16; ++reg) hacc[reg] = 0.0f;
    float mv_keep[2][16];   // msrc value per v for the z*m term (read once, fp32)

    #pragma unroll 1
    for (int v = 0; v < 2; ++v) {
        const float* msrc = v ? m_uni : m_non;
        __syncthreads();   // v=0: X-stage commit; v=1: prior M readers done
        for (int q = t; q < 64 * 32; q += 256) {
            int r = q >> 5, c4 = q & 31;
            float4 mv = make_float4(0.f, 0.f, 0.f, 0.f);
            int node = bl[r];
            if (node >= 0) mv = *(const float4*)(msrc + (size_t)node * 128 + c4 * 4);
            half4 hh, ll;
            hh[0] = hi_(mv.x); ll[0] = lo_(mv.x);
            hh[1] = hi_(mv.y); ll[1] = lo_(mv.y);
            hh[2] = hi_(mv.z); ll[2] = lo_(mv.z);
            hh[3] = hi_(mv.w); ll[3] = lo_(mv.w);
            *(half4*)(Mh + r * PX + c4 * 4) = hh;
            *(half4*)(Ml + r * PX + c4 * 4) = ll;
        }
        __syncthreads();

        const int vt = v * NTYPE + tt;
        const _Float16* pih = Wp + (size_t)(vt * 2 + 0) * 98304;
        const _Float16* phh = Wp + (size_t)(vt * 2 + 1) * 98304;

        floatx16 ar = (floatx16)0.0f, az = (floatx16)0.0f;
        floatx16 ax = (floatx16)0.0f, ah = (floatx16)0.0f;

        #pragma unroll 2
        for (int kk = 0; kk < 8; ++kk) {
            int koff = kk * 16 + hi * 8;
            int rr = r2 * 32 + lo;
            half8 xh = *(const half8*)(Xh + rr * PX + koff);
            half8 xl = *(const half8*)(Xl + rr * PX + koff);
            half8 mh = *(const half8*)(Mh + rr * PX + koff);
            half8 ml = *(const half8*)(Ml + rr * PX + koff);
            const _Float16* ci = pih + (size_t)(kk * 2 + hi) * 6144;
            const _Float16* ch = phh + (size_t)(kk * 2 + hi) * 6144;
            half8 birh = *(const half8*)(ci + (0   + d) * 8);
            half8 birl = *(const half8*)(ci + 3072 + (0   + d) * 8);
            half8 bizh = *(const half8*)(ci + (128 + d) * 8);
            half8 bizl = *(const half8*)(ci + 3072 + (128 + d) * 8);
            half8 binh = *(const half8*)(ci + (256 + d) * 8);
            half8 binl = *(const half8*)(ci + 3072 + (256 + d) * 8);
            half8 bhrh = *(const half8*)(ch + (0   + d) * 8);
            half8 bhrl = *(const half8*)(ch + 3072 + (0   + d) * 8);
            half8 bhzh = *(const half8*)(ch + (128 + d) * 8);
            half8 bhzl = *(const half8*)(ch + 3072 + (128 + d) * 8);
            half8 bhnh = *(const half8*)(ch + (256 + d) * 8);
            half8 bhnl = *(const half8*)(ch + 3072 + (256 + d) * 8);

            ar = __builtin_amdgcn_mfma_f32_32x32x16_f16(xh, birh, ar, 0, 0, 0);
            ar = __builtin_amdgcn_mfma_f32_32x32x16_f16(xh, birl, ar, 0, 0, 0);
            ar = __builtin_amdgcn_mfma_f32_32x32x16_f16(xl, birh, ar, 0, 0, 0);
            ar = __builtin_amdgcn_mfma_f32_32x32x16_f16(mh, bhrh, ar, 0, 0, 0);
            ar = __builtin_amdgcn_mfma_f32_32x32x16_f16(mh, bhrl, ar, 0, 0, 0);
            ar = __builtin_amdgcn_mfma_f32_32x32x16_f16(ml, bhrh, ar, 0, 0, 0);

            az = __builtin_amdgcn_mfma_f32_32x32x16_f16(xh, bizh, az, 0, 0, 0);
            az = __builtin_amdgcn_mfma_f32_32x32x16_f16(xh, bizl, az, 0, 0, 0);
            az = __builtin_amdgcn_mfma_f32_32x32x16_f16(xl, bizh, az, 0, 0, 0);
            az = __builtin_amdgcn_mfma_f32_32x32x16_f16(mh, bhzh, az, 0, 0, 0);
            az = __builtin_amdgcn_mfma_f32_32x32x16_f16(mh, bhzl, az, 0, 0, 0);
            az = __builtin_amdgcn_mfma_f32_32x32x16_f16(ml, bhzh, az, 0, 0, 0);

            ax = __builtin_amdgcn_mfma_f32_32x32x16_f16(xh, binh, ax, 0, 0, 0);
            ax = __builtin_amdgcn_mfma_f32_32x32x16_f16(xh, binl, ax, 0, 0, 0);
            ax = __builtin_amdgcn_mfma_f32_32x32x16_f16(xl, binh, ax, 0, 0, 0);
            ah = __builtin_amdgcn_mfma_f32_32x32x16_f16(mh, bhnh, ah, 0, 0, 0);
            ah = __builtin_amdgcn_mfma_f32_32x32x16_f16(mh, bhnl, ah, 0, 0, 0);
            ah = __builtin_amdgcn_mfma_f32_32x32x16_f16(ml, bhnh, ah, 0, 0, 0);
        }

        const float* bi = bihp + (size_t)vt * 384;
        const float* bh = bhhp + (size_t)vt * 384;
        float b_r  = bi[d] + bh[d];
        float b_z  = bi[128 + d] + bh[128 + d];
        float b_in = bi[256 + d];
        float b_hn = bh[256 + d];
        #pragma unroll
        for (int reg = 0; reg < 16; ++reg) {
            int n = r2 * 32 + drow_(reg, hi);
            int node = bl[n];
            float mv = (node >= 0) ? msrc[(size_t)node * 128 + d] : 0.0f;
            float r  = sig_(ar[reg] + b_r);
            float z  = sig_(az[reg] + b_z);
            float nv = tanhf(ax[reg] + b_in + r * (ah[reg] + b_hn));
            hacc[reg] += (1.0f - z) * nv + z * mv;
        }
    }

    // single plain store per output element (block owns these d-columns exclusively)
    #pragma unroll
    for (int reg = 0; reg < 16; ++reg) {
        int n = r2 * 32 + drow_(reg, hi);
        int node = bl[n];
        if (node >= 0) hout[(size_t)node * 128 + d] = hacc[reg];
    }
}

// ---------------------------------------------------------------- launch
extern "C" void kernel_launch(void* const* d_in, const int* in_sizes, int n_in,
                              void* d_out, int out_size, void* d_ws, size_t ws_size,
                              hipStream_t stream) {
    const float* g    = (const float*)d_in[0];
    const float* h    = (const float*)d_in[1];
    const float* msgW = (const float*)d_in[2];
    const float* Wih  = (const float*)d_in[3];
    const float* Whh  = (const float*)d_in[4];
    const float* bih  = (const float*)d_in[5];
    const float* bhh  = (const float*)d_in[6];
    float* h1 = (float*)d_out;

    char* ws = (char*)d_ws;
    float* m_non = (float*)ws;                                   // 8 MB
    float* m_uni = m_non + (size_t)NNODES * 128;                 // 8 MB
    int* counts  = (int*)(ws + 2 * (size_t)NNODES * 128 * 4);
    int* bucket  = counts + 8;                                   // [6][16384]
    int* desc    = bucket + NTYPE * NNODES;                      // [264]
    _Float16* WpM = (_Float16*)(desc + NDESC);                   // 1,835,008 halves (3.67 MB)
    _Float16* WpG = WpM + (size_t)NBOND * NLAY * 16 * 2048;      // 2,359,296 halves (4.72 MB)
    float* h0 = (float*)(WpG + (size_t)2 * NTYPE * 2 * 98304);   // 8 MB ping-pong h buffer

    (void)hipMemsetAsync(counts, 0, 8 * sizeof(int), stream);
    setup_kernel<<<NNODES * 128 / 256, 256, 0, stream>>>(h, h0, counts, bucket);
    build_desc_kernel<<<1, 64, 0, stream>>>(counts, desc);
    pack_msg_kernel<<<(NBOND * NLAY * 16 * 128 + 255) / 256, 256, 0, stream>>>(msgW, WpM);
    pack_gru_kernel<<<(2 * NTYPE * 2 * 16 * 384 + 255) / 256, 256, 0, stream>>>(Wih, Whh, WpG);

    // h ping-pong: p0 h0->h1(d_out), p1 h1->h0, p2 h0->h1(d_out)
    const float* hin_p[3]  = {h0, h1, h0};
    float*       hout_p[3] = {h1, h0, h1};
    for (int pass = 0; pass < 3; ++pass) {
        (void)hipMemsetAsync(m_non, 0, (size_t)NNODES * 128 * 4, stream);
        mlp_agg_mfma<<<dim3(NBOND, 128), 512, 0, stream>>>(hin_p[pass], WpM, g, m_non, m_uni);
        gru_mfma<<<dim3(NDESC, 2), 256, 0, stream>>>(hin_p[pass], hout_p[pass], m_non, m_uni,
                                                     counts, bucket, desc, WpG, bih, bhh);
    }
}